// Round 5
// baseline (141.003 us; speedup 1.0000x reference)
//
#include <hip/hip_runtime.h>
#include <math.h>

#define Bsz 512
#define NA  128
#define NL  512
#define Dd  128
#define KA  16
#define KL  16

#define NIDX  512                 // idx blocks (one per batch)
#define NCB   3584                // copy blocks
#define ACT4  2097152             // actor pool float4 count (512*128*128/4)
#define TOT4  10485760            // actor+lane float4 count
#define CSTRIDE (NCB * 256)       // copy grid stride in float4

// ---------------------------------------------------------------------------
// Kernel 1: blocks [0,512) = per-batch index selection.
//           blocks [512, 512+NCB) = flat float4 copy of both pools.
// ---------------------------------------------------------------------------
__global__ __launch_bounds__(256) void idx_copy_kernel(
    const float* __restrict__ spike, const unsigned char* __restrict__ avalid,
    const float* __restrict__ xc, const float* __restrict__ lc,
    const unsigned char* __restrict__ lvalid,
    const float* __restrict__ actor_feat, const float* __restrict__ lane_feat,
    int* __restrict__ aidx, int* __restrict__ lidx,
    float* __restrict__ out0, float* __restrict__ out1) {
  const int tid = threadIdx.x;

  if (blockIdx.x >= NIDX) {
    // ===================== copy role: flat streaming ======================
    const float4* __restrict__ srcA = (const float4*)actor_feat;
    const float4* __restrict__ srcL = (const float4*)lane_feat;
    float4* __restrict__ dstA = (float4*)out0;
    float4* __restrict__ dstL = (float4*)out1;
    const int gid = (blockIdx.x - NIDX) * 256 + tid;
#pragma unroll 1
    for (int base = gid; base < TOT4; base += 4 * CSTRIDE) {
      float4 v[4]; int pp[4];
#pragma unroll
      for (int u = 0; u < 4; ++u) {
        pp[u] = base + u * CSTRIDE;
        if (pp[u] < TOT4)
          v[u] = (pp[u] < ACT4) ? srcA[pp[u]] : srcL[pp[u] - ACT4];
      }
#pragma unroll
      for (int u = 0; u < 4; ++u) {
        if (pp[u] < TOT4) {
          if (pp[u] < ACT4) dstA[pp[u]] = v[u];
          else              dstL[pp[u] - ACT4] = v[u];
        }
      }
    }
    return;
  }

  // ======================= idx role: one batch per block ==================
  const int b = blockIdx.x;

  __shared__ float s_ax[KA], s_ay[KA];
  __shared__ int   s_ai[KA];
  __shared__ float s_ld[NL];
  __shared__ float s_rv[4];
  __shared__ int   s_ri[4];
  __shared__ int   s_flag;

  // ---- bool layout detection (local; av[0..4095] L2-cached across blocks):
  // int32 0/1 layout has all bytes at (i&3)!=0 zero; 1-byte bool (~50% ones)
  // has nonzero off-bytes with overwhelming probability.
  if (tid == 0) s_flag = 0;
  __syncthreads();
  {
    int any = 0;
    for (int i = tid; i < 4096; i += 256)
      if ((i & 3) && avalid[i]) any = 1;
    if (any) atomicOr(&s_flag, 1);
  }
  __syncthreads();
  const int isbyte = s_flag;

#define VALID_AT(P, I) (isbyte ? (int)(P)[I] : ((const int*)(P))[I])

  // ---- agent top-16: wave 0 only, 2 candidates per lane ----
  if (tid < 64) {
    float v0 = VALID_AT(avalid, b * NA + tid)      ? spike[b * NA + tid]      : -INFINITY;
    float v1 = VALID_AT(avalid, b * NA + tid + 64) ? spike[b * NA + tid + 64] : -INFINITY;
    for (int it = 0; it < KA; ++it) {
      float bv = v0; int bi = tid;
      if (v1 > bv) { bv = v1; bi = tid + 64; }   // tie keeps lower index
      for (int off = 32; off; off >>= 1) {
        float ov = __shfl_xor(bv, off);
        int   oi = __shfl_xor(bi, off);
        if (ov > bv || (ov == bv && oi < bi)) { bv = ov; bi = oi; }
      }
      if (bi == tid)      v0 = -INFINITY;
      if (bi == tid + 64) v1 = -INFINITY;
      if (tid == 0) s_ai[it] = bi;
    }
  }
  __syncthreads();
  if (tid < KA) {
    int a = s_ai[tid];
    aidx[b * KA + tid] = a;
    s_ax[tid] = xc[(b * NA + a) * 2 + 0];
    s_ay[tid] = xc[(b * NA + a) * 2 + 1];
  }
  __syncthreads();

  // ---- lane distances (min of squared dist; sqrt after, monotone) ----
  for (int l = tid; l < NL; l += 256) {
    float lx = lc[(b * NL + l) * 2 + 0];
    float ly = lc[(b * NL + l) * 2 + 1];
    float best = INFINITY;
#pragma unroll
    for (int a = 0; a < KA; ++a) {
      float dx = s_ax[a] - lx, dy = s_ay[a] - ly;
      float d2 = __fadd_rn(__fmul_rn(dx, dx), __fmul_rn(dy, dy));  // no fma contraction
      best = fminf(best, d2);
    }
    best = sqrtf(best);
    s_ld[l] = VALID_AT(lvalid, b * NL + l) ? best : INFINITY;
  }
  __syncthreads();

  // ---- lane top-16 smallest: block-wide iterative argmin ----
  const int wid = tid >> 6, lane = tid & 63;
  for (int it = 0; it < KL; ++it) {
    float bv = s_ld[tid]; int bi = tid;
    float v2 = s_ld[tid + 256];
    if (v2 < bv) { bv = v2; bi = tid + 256; }
    for (int off = 32; off; off >>= 1) {
      float ov = __shfl_xor(bv, off);
      int   oi = __shfl_xor(bi, off);
      if (ov < bv || (ov == bv && oi < bi)) { bv = ov; bi = oi; }
    }
    if (lane == 0) { s_rv[wid] = bv; s_ri[wid] = bi; }
    __syncthreads();
    if (tid == 0) {
      float fbv = s_rv[0]; int fbi = s_ri[0];
      for (int w = 1; w < 4; ++w)
        if (s_rv[w] < fbv || (s_rv[w] == fbv && s_ri[w] < fbi)) { fbv = s_rv[w]; fbi = s_ri[w]; }
      lidx[b * KL + it] = fbi;
      s_ld[fbi] = INFINITY;
    }
    __syncthreads();
  }
#undef VALID_AT
}

// ---------------------------------------------------------------------------
// Kernel 2: MLP for 2 batches per block, weights LDS-staged per half-matrix.
// 8 waves; each wave owns 8 rows; each lane owns output cols {lane, lane+64}.
// Reads inputs (gather), writes selected rows of out (scatter) — runs after
// the copy kernel, overwriting the stale copies of selected rows.
// ---------------------------------------------------------------------------

#define STAGE_LOAD(W, h)                                              \
  { const float4* wg4 = (const float4*)((W) + (h) * 8192);            \
    R0 = wg4[tid]; R1 = wg4[512 + tid];                               \
    R2 = wg4[1024 + tid]; R3 = wg4[1536 + tid]; }

#define STAGE_WRITE()                                                 \
  { float4* swg4 = (float4*)s_w;                                      \
    swg4[tid] = R0; swg4[512 + tid] = R1;                             \
    swg4[1024 + tid] = R2; swg4[1536 + tid] = R3; }

#define FMA_HALF(h)                                                   \
  _Pragma("unroll 4")                                                 \
  for (int g = 0; g < 16; ++g) {                                      \
    const float* wr = s_w + g * 4 * Dd;                               \
    float w00 = wr[j0],        w10 = wr[j1];                          \
    float w01 = wr[Dd + j0],   w11 = wr[Dd + j1];                     \
    float w02 = wr[2*Dd + j0], w12 = wr[2*Dd + j1];                   \
    float w03 = wr[3*Dd + j0], w13 = wr[3*Dd + j1];                   \
    _Pragma("unroll")                                                 \
    for (int n = 0; n < 8; ++n) {                                     \
      float4 xv = ((const float4*)s_xu[n0 + n])[(h) * 16 + g];        \
      acc0[n] = fmaf(xv.x, w00, acc0[n]); acc1[n] = fmaf(xv.x, w10, acc1[n]); \
      acc0[n] = fmaf(xv.y, w01, acc0[n]); acc1[n] = fmaf(xv.y, w11, acc1[n]); \
      acc0[n] = fmaf(xv.z, w02, acc0[n]); acc1[n] = fmaf(xv.z, w12, acc1[n]); \
      acc0[n] = fmaf(xv.w, w03, acc0[n]); acc1[n] = fmaf(xv.w, w13, acc1[n]); \
    }                                                                 \
  }

#define MATVEC(W, Bv)                                                 \
  { const float bias0 = (Bv)[j0], bias1 = (Bv)[j1];                   \
    _Pragma("unroll")                                                 \
    for (int n = 0; n < 8; ++n) { acc0[n] = bias0; acc1[n] = bias1; } \
    STAGE_LOAD(W, 0);                                                 \
    STAGE_WRITE(); __syncthreads();                                   \
    STAGE_LOAD(W, 1);                                                 \
    FMA_HALF(0);                                                      \
    __syncthreads();                                                  \
    STAGE_WRITE(); __syncthreads();                                   \
    FMA_HALF(1);                                                      \
    __syncthreads(); }

__global__ __launch_bounds__(512, 2) void mlp_kernel(
    const float* __restrict__ actor_feat, const float* __restrict__ lane_feat,
    const int* __restrict__ aidx, const int* __restrict__ lidx,
    const float* __restrict__ W0a, const float* __restrict__ b0a,
    const float* __restrict__ W0b, const float* __restrict__ b0b,
    const float* __restrict__ W1a, const float* __restrict__ b1a,
    const float* __restrict__ W1b, const float* __restrict__ b1b,
    const float* __restrict__ gamma, const float* __restrict__ beta,
    float* __restrict__ out0, float* __restrict__ out1) {
  __shared__ float s_w[64 * Dd];      // 32 KB: half weight matrix
  __shared__ float s_xu[64][Dd];      // 32 KB: 2 batches x 32 rows
  __shared__ int   s_src[64];

  const int tid = threadIdx.x;
  const int wave = tid >> 6, lane = tid & 63;
  const int b0 = blockIdx.x * 2;

  if (tid < 64) {
    int rr = tid, bidx = b0 + (rr >> 5), lr = rr & 31;
    s_src[rr] = (lr < 16) ? aidx[bidx * KA + lr] : lidx[bidx * KL + lr - 16];
  }
  __syncthreads();

  const int n0 = wave * 8;
  // gather own 8 rows (wave-private thereafter)
#pragma unroll
  for (int i = 0; i < 4; ++i) {
    int q = lane + 64 * i;
    int rr = n0 + (q >> 5), c4 = q & 31;
    int bidx = b0 + (rr >> 5), lr = rr & 31;
    const float* src = (lr < 16)
        ? actor_feat + ((size_t)bidx * NA + s_src[rr]) * Dd
        : lane_feat  + ((size_t)bidx * NL + s_src[rr]) * Dd;
    ((float4*)s_xu[rr])[c4] = ((const float4*)src)[c4];
  }

  const int j0 = lane, j1 = lane + 64;
  const float g0 = gamma[j0], g1 = gamma[j1];
  const float bt0 = beta[j0], bt1 = beta[j1];

  float acc0[8], acc1[8], rx0[8], rx1[8];
  float4 R0, R1, R2, R3;

#pragma unroll
  for (int n = 0; n < 8; ++n) {
    rx0[n] = s_xu[n0 + n][j0];
    rx1[n] = s_xu[n0 + n][j1];
  }

#pragma unroll 1
  for (int layer = 0; layer < 2; ++layer) {
    const float* wa = layer ? W1a : W0a;
    const float* ba = layer ? b1a : b0a;
    const float* wb = layer ? W1b : W0b;
    const float* bb = layer ? b1b : b0b;

    // ---- t = x @ Wa + ba ----
    MATVEC(wa, ba);

    // ---- exact GELU -> overwrite own s_xu rows with u ----
#pragma unroll
    for (int n = 0; n < 8; ++n) {
      float t0 = acc0[n], t1 = acc1[n];
      s_xu[n0 + n][j0] = 0.5f * t0 * (1.0f + erff(t0 * 0.70710678118654752f));
      s_xu[n0 + n][j1] = 0.5f * t1 * (1.0f + erff(t1 * 0.70710678118654752f));
    }

    // ---- h = gelu(t) @ Wb + bb ----
    MATVEC(wb, bb);

    // ---- residual + LayerNorm ----
#pragma unroll
    for (int n = 0; n < 8; ++n) {
      float r0 = rx0[n] + acc0[n];
      float r1 = rx1[n] + acc1[n];
      float sum = r0 + r1;
      for (int off = 32; off; off >>= 1) sum += __shfl_xor(sum, off);
      float mean = sum * (1.0f / 128.0f);
      float d0 = r0 - mean, d1 = r1 - mean;
      float sq = d0 * d0 + d1 * d1;
      for (int off = 32; off; off >>= 1) sq += __shfl_xor(sq, off);
      float inv = 1.0f / sqrtf(sq * (1.0f / 128.0f) + 1e-5f);
      float v0 = d0 * inv * g0 + bt0;
      float v1 = d1 * inv * g1 + bt1;
      if (layer == 0) {
        s_xu[n0 + n][j0] = v0; s_xu[n0 + n][j1] = v1;   // layer-1 input
        rx0[n] = v0; rx1[n] = v1;                       // layer-1 residual
      } else {
        int rr = n0 + n, bidx = b0 + (rr >> 5), lr = rr & 31, si = s_src[rr];
        float* dst = (lr < 16) ? out0 + ((size_t)bidx * NA + si) * Dd
                               : out1 + ((size_t)bidx * NL + si) * Dd;
        dst[j0] = v0;
        dst[j1] = v1;
      }
    }
  }
}

// ---------------------------------------------------------------------------
extern "C" void kernel_launch(void* const* d_in, const int* in_sizes, int n_in,
                              void* d_out, int out_size, void* d_ws, size_t ws_size,
                              hipStream_t stream) {
  const float* actor_feat = (const float*)d_in[0];
  const float* lane_feat  = (const float*)d_in[1];
  const float* lc         = (const float*)d_in[2];
  const float* xc         = (const float*)d_in[3];
  const float* spike      = (const float*)d_in[4];
  const unsigned char* avalid = (const unsigned char*)d_in[5];
  const unsigned char* lvalid = (const unsigned char*)d_in[6];
  const float* W0a = (const float*)d_in[7];
  const float* b0a = (const float*)d_in[8];
  const float* W0b = (const float*)d_in[9];
  const float* b0b = (const float*)d_in[10];
  const float* W1a = (const float*)d_in[11];
  const float* b1a = (const float*)d_in[12];
  const float* W1b = (const float*)d_in[13];
  const float* b1b = (const float*)d_in[14];
  const float* gamma = (const float*)d_in[15];
  const float* beta  = (const float*)d_in[16];

  int* aidx = (int*)d_ws;
  int* lidx = aidx + Bsz * KA;

  float* out0 = (float*)d_out;
  float* out1 = out0 + (size_t)Bsz * NA * Dd;

  idx_copy_kernel<<<NIDX + NCB, 256, 0, stream>>>(
      spike, avalid, xc, lc, lvalid, actor_feat, lane_feat,
      aidx, lidx, out0, out1);
  mlp_kernel<<<Bsz / 2, 512, 0, stream>>>(
      actor_feat, lane_feat, aidx, lidx,
      W0a, b0a, W0b, b0b, W1a, b1a, W1b, b1b, gamma, beta, out0, out1);
}